// Round 3
// baseline (701.858 us; speedup 1.0000x reference)
//
#include <hip/hip_runtime.h>
#include <hip/hip_bf16.h>

#define T_TOK 4096
#define H_DIM 1024
#define E_EXP 64
#define TOPK  8
#define F_DIM 512
#define CAP   1024
#define A_TOT (T_TOK * TOPK)   // 32768

typedef _Float16 f16;
typedef _Float16 f16x8 __attribute__((ext_vector_type(8)));
typedef float    f32x4 __attribute__((ext_vector_type(4)));

// ---------------------------------------------------------------------------
// K0 v3: all three weight packs in ONE launch. fp32 [E][Kd][Nd] -> fp16
// B-fragment chunks [e][nt][kt] of 512 f16. Chunk (e,nt,kt): lane l, slot j
// holds src[e][kt*32+(l>>4)*8+j][nt*16+(l&15)]. Direct gather, no LDS.
// w1: chunks [0,65536) Kd=1024,Nd=512; w3: [65536,131072); w2: [131072,196608)
// Kd=512,Nd=1024. One chunk per wave, 4 per block, grid 49152.
// ---------------------------------------------------------------------------
__global__ __launch_bounds__(256) void pack_all_kernel(
    const float* __restrict__ w1, const float* __restrict__ w3,
    const float* __restrict__ w2,
    f16* __restrict__ w1p, f16* __restrict__ w3p, f16* __restrict__ w2p)
{
    const int tid  = threadIdx.x;
    const int lane = tid & 63, wv = tid >> 6;
    int cid = blockIdx.x * 4 + wv;
    const float* src; f16* dst; int Kd, Nd;
    if (cid < 65536)       { src = w1; dst = w1p; Kd = 1024; Nd = 512; }
    else if (cid < 131072) { src = w3; dst = w3p; Kd = 1024; Nd = 512; cid -= 65536; }
    else                   { src = w2; dst = w2p; Kd = 512;  Nd = 1024; cid -= 131072; }
    const int kbs = __builtin_ctz(Kd >> 5);    // log2(k-chunks)
    const int nts = __builtin_ctz(Nd >> 4);    // log2(n-tiles)
    const int kt = cid & ((1 << kbs) - 1);
    const int en = cid >> kbs;
    const int nt = en & ((1 << nts) - 1);
    const int e  = en >> nts;
    const int jj = lane & 15, qq = lane >> 4;
    const float* s = src + ((size_t)e * Kd + kt * 32 + qq * 8) * Nd + nt * 16 + jj;
    f16x8 v;
    #pragma unroll
    for (int j = 0; j < 8; ++j) v[j] = (f16)s[(size_t)j * Nd];
    *(f16x8*)(dst + (size_t)cid * 512 + (size_t)(blockIdx.x * 4 + wv >= 131072 ? 0 : 0) + lane * 8) = v;
}

// ---------------------------------------------------------------------------
// K1: router — fp32 logits, top-8 (stable), renormalized weights; emits fp16 x.
// ---------------------------------------------------------------------------
__global__ __launch_bounds__(256) void router_kernel(
    const float* __restrict__ x, const float* __restrict__ wg,
    float* __restrict__ logits_out, int* __restrict__ sel,
    float* __restrict__ wgtA, f16* __restrict__ xh)
{
    __shared__ float xs[16][128];
    __shared__ float ls[16][65];
    const int tid = threadIdx.x;
    const int e  = tid & 63;
    const int tg = tid >> 6;
    const int tb = blockIdx.x * 16;

    float acc[4] = {0.f, 0.f, 0.f, 0.f};
    for (int h0 = 0; h0 < H_DIM; h0 += 128) {
        {
            int r  = tid >> 4;
            int c0 = (tid & 15) * 8;
            const float4* src = (const float4*)(x + (size_t)(tb + r) * H_DIM + h0 + c0);
            float4 v0 = src[0], v1 = src[1];
            *(float4*)&xs[r][c0]     = v0;
            *(float4*)&xs[r][c0 + 4] = v1;
            f16x8 hv;
            hv[0] = (f16)v0.x; hv[1] = (f16)v0.y; hv[2] = (f16)v0.z; hv[3] = (f16)v0.w;
            hv[4] = (f16)v1.x; hv[5] = (f16)v1.y; hv[6] = (f16)v1.z; hv[7] = (f16)v1.w;
            *(f16x8*)(xh + (size_t)(tb + r) * H_DIM + h0 + c0) = hv;
        }
        __syncthreads();
        for (int hh = 0; hh < 128; ++hh) {
            float w = wg[(size_t)(h0 + hh) * E_EXP + e];
            #pragma unroll
            for (int i = 0; i < 4; ++i)
                acc[i] = fmaf(xs[tg * 4 + i][hh], w, acc[i]);
        }
        __syncthreads();
    }
    #pragma unroll
    for (int i = 0; i < 4; ++i) {
        int tt = tg * 4 + i;
        logits_out[(size_t)(tb + tt) * E_EXP + e] = acc[i];
        ls[tt][e] = acc[i];
    }
    __syncthreads();
    if (tid < 16) {
        int tt = tid;
        float lv[8]; int li[8];
        for (int k = 0; k < 8; ++k) {
            float m = -1e30f; int mi = 0;
            for (int j = 0; j < 64; ++j) {
                float v = ls[tt][j];
                if (v > m) { m = v; mi = j; }   // strict > : lowest index wins (stable)
            }
            lv[k] = m; li[k] = mi;
            ls[tt][mi] = -1e30f;
        }
        float s = 0.f, wv[8];
        for (int k = 0; k < 8; ++k) { wv[k] = __expf(lv[k] - lv[0]); s += wv[k]; }
        float inv = 1.f / s;
        for (int k = 0; k < 8; ++k) {
            int a = (tb + tt) * TOPK + k;
            sel[a]  = li[k];
            wgtA[a] = wv[k] * inv;
        }
    }
}

// ---------------------------------------------------------------------------
// K2: per-expert stable token lists + capacity drop (matches argsort(stable)).
// Also emits the inverse map slotA[a] = e*CAP+pos (-1 if dropped) for combine.
// ---------------------------------------------------------------------------
__global__ __launch_bounds__(256) void build_lists_kernel(
    const int* __restrict__ sel,
    int* __restrict__ tok_list, int* __restrict__ slotA,
    int* __restrict__ counts)
{
    __shared__ int sc[256];
    const int e = blockIdx.x;
    const int tid = threadIdx.x;
    const int per = A_TOT / 256;
    const int a0 = tid * per;
    int cnt = 0;
    for (int i = 0; i < per; ++i) cnt += (sel[a0 + i] == e) ? 1 : 0;
    sc[tid] = cnt;
    __syncthreads();
    for (int s = 1; s < 256; s <<= 1) {
        int v = (tid >= s) ? sc[tid - s] : 0;
        __syncthreads();
        sc[tid] += v;
        __syncthreads();
    }
    int total = sc[255];
    int pos = sc[tid] - cnt;
    if (tid == 0) counts[e] = (total < CAP) ? total : CAP;
    for (int i = 0; i < per; ++i) {
        int a = a0 + i;
        if (sel[a] == e) {
            if (pos < CAP) {
                tok_list[e * CAP + pos] = a >> 3;
                slotA[a] = e * CAP + pos;
            } else {
                slotA[a] = -1;                  // dropped (never happens at CAP_FACTOR=2)
            }
            pos++;
        }
    }
}

#define MFMA16(a, b, c) __builtin_amdgcn_mfma_f32_16x16x32_f16(a, b, c, 0, 0, 0)

// ---------------------------------------------------------------------------
// K3a v4: P = silu(x@w1)*(x@w3). BM=128 rows x BN=64 F-cols, 512 thr (8 waves,
// 4M x 2N). Per wave: 2 m-frags x (2 G + 2 U n-tiles) -> acc 8 f32x4 (32 AGPR,
// half of v3) + same 8+8 f16x8 weight prefetch regs -> ~120 regs total ->
// 4 waves/SIMD, 2 blocks/CU (50% occupancy; v3 measured 19%). M=128 also
// halves the per-expert weight re-read: L3 weight stream 1 GB -> 512 MB.
// XOR-swizzled unpadded LDS (0 bank conflicts, measured). XCD pinning (e&7).
// ---------------------------------------------------------------------------
__global__ __launch_bounds__(512) void gemm1_kernel(
    const f16* __restrict__ xh, const f16* __restrict__ w1p,
    const f16* __restrict__ w3p, const int* __restrict__ tok_list,
    const int* __restrict__ counts, f16* __restrict__ P)
{
    const int id = blockIdx.x;
    const int x7 = id & 7, r = id >> 3;
    const int ft = r & 7, mt = (r >> 3) & 7, eh = r >> 6;
    const int e = x7 + 8 * eh;
    const int cnt = counts[e];
    const int m0 = mt * 128;
    if (m0 >= cnt) return;
    const int bf = ft * 64;

    __shared__ f16 Xs[2][128][64];
    __shared__ int tok_s[128];

    const int tid = threadIdx.x;
    const int lane = tid & 63, wv = tid >> 6;
    const int wm = wv >> 1, wn = wv & 1;
    const int jj = lane & 15, qq = lane >> 4;
    const int sr = tid >> 3, sc = (tid & 7) * 8;      // sr 0..63 (rows sr, sr+64)
    const int swz_w = ((tid & 7) ^ (sr & 7)) * 8;     // swizzled write slot
    const int x8 = jj & 15 & 7;
    const int s0 = (qq ^ x8) * 8;                     // swizzled read slot, k-half 0
    const int s1 = ((qq + 4) ^ x8) * 8;               // swizzled read slot, k-half 1

    if (tid < 128) {
        int m = m0 + tid;
        tok_s[tid] = (m < cnt) ? tok_list[e * CAP + m] : tok_list[e * CAP];
    }
    __syncthreads();
    const size_t rowA = (size_t)tok_s[sr] * H_DIM + sc;
    const size_t rowB = (size_t)tok_s[sr + 64] * H_DIM + sc;

    const int ntA = ft * 4 + wn * 2;                  // first of 2 n-tiles
    const f16* w1a = w1p + ((size_t)(e * 32 + ntA) * 32) * 512 + lane * 8;
    const f16* w3a = w3p + ((size_t)(e * 32 + ntA) * 32) * 512 + lane * 8;
    // n-tile stride in packed layout = kb*512 = 32*512 = 16384 f16

    f32x4 accG[2][2], accU[2][2];                     // [m2][nt]
    #pragma unroll
    for (int i = 0; i < 2; ++i)
        #pragma unroll
        for (int n = 0; n < 2; ++n) {
            accG[i][n] = (f32x4){0.f, 0.f, 0.f, 0.f};
            accU[i][n] = (f32x4){0.f, 0.f, 0.f, 0.f};
        }

    // prologue: stage k-block 0 + first weight frags
    {
        f16x8 a = *(const f16x8*)(xh + rowA);
        f16x8 b = *(const f16x8*)(xh + rowB);
        *(f16x8*)&Xs[0][sr][swz_w]      = a;
        *(f16x8*)&Xs[0][sr + 64][swz_w] = b;
    }
    f16x8 cG[4], cU[4];   // [ntile*2 + khalf]
    cG[0] = *(const f16x8*)(w1a);
    cG[1] = *(const f16x8*)(w1a + 512);
    cG[2] = *(const f16x8*)(w1a + 16384);
    cG[3] = *(const f16x8*)(w1a + 16384 + 512);
    cU[0] = *(const f16x8*)(w3a);
    cU[1] = *(const f16x8*)(w3a + 512);
    cU[2] = *(const f16x8*)(w3a + 16384);
    cU[3] = *(const f16x8*)(w3a + 16384 + 512);

    #pragma unroll
    for (int it = 0; it < 16; ++it) {
        const int k0 = it * 64;
        __syncthreads();                       // Xs[it&1] visible; prior readers of Xs[(it+1)&1] done
        f16x8 xn0, xn1, nG[4], nU[4];
        if (it < 15) {                         // issue next-iter loads before MFMAs
            xn0 = *(const f16x8*)(xh + rowA + k0 + 64);
            xn1 = *(const f16x8*)(xh + rowB + k0 + 64);
            size_t kg = (size_t)(2 * it + 2) * 512;
            nG[0] = *(const f16x8*)(w1a + kg);
            nG[1] = *(const f16x8*)(w1a + kg + 512);
            nG[2] = *(const f16x8*)(w1a + kg + 16384);
            nG[3] = *(const f16x8*)(w1a + kg + 16384 + 512);
            nU[0] = *(const f16x8*)(w3a + kg);
            nU[1] = *(const f16x8*)(w3a + kg + 512);
            nU[2] = *(const f16x8*)(w3a + kg + 16384);
            nU[3] = *(const f16x8*)(w3a + kg + 16384 + 512);
        }
        const int buf = it & 1;
        #pragma unroll
        for (int m2 = 0; m2 < 2; ++m2) {
            f16x8 a0 = *(const f16x8*)&Xs[buf][wm * 32 + m2 * 16 + jj][s0];
            f16x8 a1 = *(const f16x8*)&Xs[buf][wm * 32 + m2 * 16 + jj][s1];
            accG[m2][0] = MFMA16(a0, cG[0], accG[m2][0]);
            accG[m2][0] = MFMA16(a1, cG[1], accG[m2][0]);
            accG[m2][1] = MFMA16(a0, cG[2], accG[m2][1]);
            accG[m2][1] = MFMA16(a1, cG[3], accG[m2][1]);
            accU[m2][0] = MFMA16(a0, cU[0], accU[m2][0]);
            accU[m2][0] = MFMA16(a1, cU[1], accU[m2][0]);
            accU[m2][1] = MFMA16(a0, cU[2], accU[m2][1]);
            accU[m2][1] = MFMA16(a1, cU[3], accU[m2][1]);
        }
        if (it < 15) {
            *(f16x8*)&Xs[buf ^ 1][sr][swz_w]      = xn0;
            *(f16x8*)&Xs[buf ^ 1][sr + 64][swz_w] = xn1;
            #pragma unroll
            for (int i = 0; i < 4; ++i) { cG[i] = nG[i]; cU[i] = nU[i]; }
        }
    }
    #pragma unroll
    for (int m2 = 0; m2 < 2; ++m2) {
        #pragma unroll
        for (int n = 0; n < 2; ++n) {
            #pragma unroll
            for (int rr = 0; rr < 4; ++rr) {
                int row = wm * 32 + m2 * 16 + qq * 4 + rr;
                float gg = accG[m2][n][rr], u = accU[m2][n][rr];
                float p = gg / (1.f + __expf(-gg)) * u;
                P[(size_t)(e * CAP + m0 + row) * F_DIM + bf + (wn * 2 + n) * 16 + jj] = (f16)p;
            }
        }
    }
}

// ---------------------------------------------------------------------------
// K3b v4: Y = P @ w2 into slot-indexed Y[E*CAP][H] (plain f16 stores).
// BM=128 x BN=128 h-cols, 512 thr (8 waves, 4M x 2N); wave = 2 m-frags x
// 4 n-tiles. Same swizzled LDS + pipeline + occupancy profile as gemm1 v4.
// Weight re-read halves: L3 w2 stream 512 MB -> 256 MB.
// ---------------------------------------------------------------------------
__global__ __launch_bounds__(512) void gemm2_kernel(
    const f16* __restrict__ P, const f16* __restrict__ w2p,
    const int* __restrict__ counts, f16* __restrict__ Y)
{
    const int id = blockIdx.x;
    const int x7 = id & 7, r = id >> 3;
    const int ht = r & 7, mt = (r >> 3) & 7, eh = r >> 6;
    const int e = x7 + 8 * eh;
    const int cnt = counts[e];
    const int m0 = mt * 128;
    if (m0 >= cnt) return;
    const int h0 = ht * 128;

    __shared__ f16 Ps[2][128][64];

    const int tid = threadIdx.x;
    const int lane = tid & 63, wv = tid >> 6;
    const int wm = wv >> 1, wn = wv & 1;
    const int jj = lane & 15, qq = lane >> 4;
    const int sr = tid >> 3, sc = (tid & 7) * 8;
    const int swz_w = ((tid & 7) ^ (sr & 7)) * 8;
    const int x8 = jj & 7;
    const int s0 = (qq ^ x8) * 8;
    const int s1 = ((qq + 4) ^ x8) * 8;

    const size_t pbase = (size_t)(e * CAP + m0) * F_DIM;
    const int nt0 = ht * 8 + wn * 4;                  // first of 4 n-tiles
    const f16* wb = w2p + ((size_t)(e * 64 + nt0) * 16) * 512 + lane * 8;
    // n-tile stride = kb*512 = 16*512 = 8192 f16

    f32x4 acc[2][4];
    #pragma unroll
    for (int i = 0; i < 2; ++i)
        #pragma unroll
        for (int n = 0; n < 4; ++n)
            acc[i][n] = (f32x4){0.f, 0.f, 0.f, 0.f};

    {
        f16x8 a = *(const f16x8*)(P + pbase + (size_t)sr * F_DIM + sc);
        f16x8 b = *(const f16x8*)(P + pbase + (size_t)(sr + 64) * F_DIM + sc);
        *(f16x8*)&Ps[0][sr][swz_w]      = a;
        *(f16x8*)&Ps[0][sr + 64][swz_w] = b;
    }
    f16x8 cW[8];   // [ntile*2 + khalf]
    #pragma unroll
    for (int i = 0; i < 4; ++i) {
        cW[i * 2]     = *(const f16x8*)(wb + (size_t)i * 8192);
        cW[i * 2 + 1] = *(const f16x8*)(wb + (size_t)i * 8192 + 512);
    }

    #pragma unroll
    for (int it = 0; it < 8; ++it) {
        const int k0 = it * 64;
        __syncthreads();
        f16x8 pn0, pn1, nW[8];
        if (it < 7) {
            pn0 = *(const f16x8*)(P + pbase + (size_t)sr * F_DIM + k0 + 64 + sc);
            pn1 = *(const f16x8*)(P + pbase + (size_t)(sr + 64) * F_DIM + k0 + 64 + sc);
            size_t kg = (size_t)(2 * it + 2) * 512;
            #pragma unroll
            for (int i = 0; i < 4; ++i) {
                nW[i * 2]     = *(const f16x8*)(wb + (size_t)i * 8192 + kg);
                nW[i * 2 + 1] = *(const f16x8*)(wb + (size_t)i * 8192 + kg + 512);
            }
        }
        const int buf = it & 1;
        #pragma unroll
        for (int m2 = 0; m2 < 2; ++m2) {
            f16x8 a0 = *(const f16x8*)&Ps[buf][wm * 32 + m2 * 16 + jj][s0];
            f16x8 a1 = *(const f16x8*)&Ps[buf][wm * 32 + m2 * 16 + jj][s1];
            #pragma unroll
            for (int i = 0; i < 4; ++i) {
                acc[m2][i] = MFMA16(a0, cW[i * 2],     acc[m2][i]);
                acc[m2][i] = MFMA16(a1, cW[i * 2 + 1], acc[m2][i]);
            }
        }
        if (it < 7) {
            *(f16x8*)&Ps[buf ^ 1][sr][swz_w]      = pn0;
            *(f16x8*)&Ps[buf ^ 1][sr + 64][swz_w] = pn1;
            #pragma unroll
            for (int i = 0; i < 8; ++i) cW[i] = nW[i];
        }
    }
    // plain f16 stores; rows >= cnt write dead slots never referenced by combine
    f16* yb = Y + (size_t)(e * CAP + m0) * H_DIM + h0 + wn * 64 + jj;
    #pragma unroll
    for (int m2 = 0; m2 < 2; ++m2) {
        #pragma unroll
        for (int rr = 0; rr < 4; ++rr) {
            int row = wm * 32 + m2 * 16 + qq * 4 + rr;
            #pragma unroll
            for (int i = 0; i < 4; ++i)
                yb[(size_t)row * H_DIM + i * 16] = (f16)acc[m2][i][rr];
        }
    }
}

// ---------------------------------------------------------------------------
// K4: combine — out[t] = sum_k wgt[t,k] * Y[slot[t,k]]. Streaming gather;
// fully overwrites out (no memset needed). 2 tokens/block, 128 thr/token.
// ---------------------------------------------------------------------------
__global__ __launch_bounds__(256) void combine_kernel(
    const f16* __restrict__ Y, const int* __restrict__ slotA,
    const float* __restrict__ wgtA, float* __restrict__ out)
{
    const int tid = threadIdx.x;
    const int t  = blockIdx.x * 2 + (tid >> 7);
    const int hc = (tid & 127) * 8;
    float acc[8] = {0.f, 0.f, 0.f, 0.f, 0.f, 0.f, 0.f, 0.f};
    const int base = t * TOPK;
    #pragma unroll
    for (int k = 0; k < 8; ++k) {
        int s   = slotA[base + k];      // wave-uniform
        float w = wgtA[base + k];
        if (s >= 0) {
            f16x8 y = *(const f16x8*)(Y + (size_t)s * H_DIM + hc);
            #pragma unroll
            for (int j = 0; j < 8; ++j) acc[j] += w * (float)y[j];
        }
    }
    float4 o0 = {acc[0], acc[1], acc[2], acc[3]};
    float4 o1 = {acc[4], acc[5], acc[6], acc[7]};
    *(float4*)(out + (size_t)t * H_DIM + hc)     = o0;
    *(float4*)(out + (size_t)t * H_DIM + hc + 4) = o1;
}

extern "C" void kernel_launch(void* const* d_in, const int* in_sizes, int n_in,
                              void* d_out, int out_size, void* d_ws, size_t ws_size,
                              hipStream_t stream) {
    const float* x  = (const float*)d_in[0];   // [T,H]
    const float* wg = (const float*)d_in[1];   // [H,E]
    const float* w1 = (const float*)d_in[2];   // [E,H,F]
    const float* w3 = (const float*)d_in[3];   // [E,H,F]
    const float* w2 = (const float*)d_in[4];   // [E,F,H]

    float* out    = (float*)d_out;
    float* logits = out + (size_t)T_TOK * H_DIM;

    char* ws = (char*)d_ws;
    int*   sel      = (int*)  (ws);
    float* wgtA     = (float*)(ws + (128 << 10));
    int*   tok_list = (int*)  (ws + (256 << 10));
    int*   slotA    = (int*)  (ws + (512 << 10));
    int*   counts   = (int*)  (ws + (768 << 10));
    f16*   xh       = (f16*)  (ws + (size_t)(1 << 20));     // 8 MB
    f16*   P        = (f16*)  (ws + (size_t)(9 << 20));     // 64 MB
    f16*   w1p      = (f16*)  (ws + (size_t)(73 << 20));    // 64 MB
    f16*   w3p      = (f16*)  (ws + (size_t)(137 << 20));   // 64 MB
    f16*   w2p      = (f16*)  (ws + (size_t)(201 << 20));   // 64 MB (end 265 MB)
    // Y aliases w1p+w3p (dead after gemm1; same-stream ordering makes this safe)
    f16*   Y        = (f16*)  (ws + (size_t)(73 << 20));    // 128 MB [E*CAP, H]

    pack_all_kernel<<<49152, 256, 0, stream>>>(w1, w3, w2, w1p, w3p, w2p);
    router_kernel<<<T_TOK / 16, 256, 0, stream>>>(x, wg, logits, sel, wgtA, xh);
    build_lists_kernel<<<E_EXP, 256, 0, stream>>>(sel, tok_list, slotA, counts);
    gemm1_kernel<<<4096, 512, 0, stream>>>(xh, w1p, w3p, tok_list, counts, P);
    gemm2_kernel<<<4096, 512, 0, stream>>>(P, w2p, counts, Y);
    combine_kernel<<<T_TOK / 2, 256, 0, stream>>>(Y, slotA, wgtA, out);
}

// Round 4
// 655.379 us; speedup vs baseline: 1.0709x; 1.0709x over previous
//
#include <hip/hip_runtime.h>
#include <hip/hip_bf16.h>

#define T_TOK 4096
#define H_DIM 1024
#define E_EXP 64
#define TOPK  8
#define F_DIM 512
#define CAP   1024
#define A_TOT (T_TOK * TOPK)   // 32768

typedef _Float16 f16;
typedef _Float16 f16x8 __attribute__((ext_vector_type(8)));
typedef float    f32x4 __attribute__((ext_vector_type(4)));

// ---------------------------------------------------------------------------
// K0 v4: all three packs, one launch, FULL-LINE reads. fp32 [E][Kd][Nd] ->
// fp16 B-fragment chunks [e][nt][kt] of 512 f16 (lane l slot j =
// src[kt*32+(l>>4)*8+j][nt*16+(l&15)]). Each wave packs an ADJACENT n-tile
// PAIR: quarter-wave reads cols ntp*32..ntp*32+31 = 128B = a full cache line
// (v3 read 64B halves -> 3.2 TB/s, 40% peak). 16 loads in flight per lane.
// w1 pairs [0,32768), w3 [32768,65536), w2 [65536,98304). 4 pairs/block.
// ---------------------------------------------------------------------------
__global__ __launch_bounds__(256) void pack_all_kernel(
    const float* __restrict__ w1, const float* __restrict__ w3,
    const float* __restrict__ w2,
    f16* __restrict__ w1p, f16* __restrict__ w3p, f16* __restrict__ w2p)
{
    const int tid  = threadIdx.x;
    const int lane = tid & 63, wvi = tid >> 6;
    int pid = blockIdx.x * 4 + wvi;
    const float* src; f16* dst; int Nd, kb, kbs, nps;
    if (pid < 32768)      { src = w1; dst = w1p; Nd = 512;  kb = 32; kbs = 5; nps = 4; }
    else if (pid < 65536) { src = w3; dst = w3p; Nd = 512;  kb = 32; kbs = 5; nps = 4; pid -= 32768; }
    else                  { src = w2; dst = w2p; Nd = 1024; kb = 16; kbs = 4; nps = 5; pid -= 65536; }
    const int kt  = pid & (kb - 1);
    const int en  = pid >> kbs;
    const int ntp = en & ((1 << nps) - 1);    // n-tile-pair index
    const int e   = en >> nps;
    const int Kd  = kb << 5;
    const int jj = lane & 15, qq = lane >> 4;
    const float* s = src + ((size_t)e * Kd + kt * 32 + qq * 8) * Nd + ntp * 32 + jj;
    f16x8 v0, v1;
    #pragma unroll
    for (int j = 0; j < 8; ++j) {
        float a = s[(size_t)j * Nd];
        float b = s[(size_t)j * Nd + 16];
        v0[j] = (f16)a;
        v1[j] = (f16)b;
    }
    size_t c0 = (size_t)(e * (Nd >> 4) + ntp * 2) * kb + kt;
    *(f16x8*)(dst + c0 * 512 + lane * 8)        = v0;
    *(f16x8*)(dst + (c0 + kb) * 512 + lane * 8) = v1;   // nt+1 is kb chunks later
}

// ---------------------------------------------------------------------------
// K1: router — fp32 logits, top-8 (stable), renormalized weights; emits fp16 x.
// ---------------------------------------------------------------------------
__global__ __launch_bounds__(256) void router_kernel(
    const float* __restrict__ x, const float* __restrict__ wg,
    float* __restrict__ logits_out, int* __restrict__ sel,
    float* __restrict__ wgtA, f16* __restrict__ xh)
{
    __shared__ float xs[16][128];
    __shared__ float ls[16][65];
    const int tid = threadIdx.x;
    const int e  = tid & 63;
    const int tg = tid >> 6;
    const int tb = blockIdx.x * 16;

    float acc[4] = {0.f, 0.f, 0.f, 0.f};
    for (int h0 = 0; h0 < H_DIM; h0 += 128) {
        {
            int r  = tid >> 4;
            int c0 = (tid & 15) * 8;
            const float4* src = (const float4*)(x + (size_t)(tb + r) * H_DIM + h0 + c0);
            float4 v0 = src[0], v1 = src[1];
            *(float4*)&xs[r][c0]     = v0;
            *(float4*)&xs[r][c0 + 4] = v1;
            f16x8 hv;
            hv[0] = (f16)v0.x; hv[1] = (f16)v0.y; hv[2] = (f16)v0.z; hv[3] = (f16)v0.w;
            hv[4] = (f16)v1.x; hv[5] = (f16)v1.y; hv[6] = (f16)v1.z; hv[7] = (f16)v1.w;
            *(f16x8*)(xh + (size_t)(tb + r) * H_DIM + h0 + c0) = hv;
        }
        __syncthreads();
        for (int hh = 0; hh < 128; ++hh) {
            float w = wg[(size_t)(h0 + hh) * E_EXP + e];
            #pragma unroll
            for (int i = 0; i < 4; ++i)
                acc[i] = fmaf(xs[tg * 4 + i][hh], w, acc[i]);
        }
        __syncthreads();
    }
    #pragma unroll
    for (int i = 0; i < 4; ++i) {
        int tt = tg * 4 + i;
        logits_out[(size_t)(tb + tt) * E_EXP + e] = acc[i];
        ls[tt][e] = acc[i];
    }
    __syncthreads();
    if (tid < 16) {
        int tt = tid;
        float lv[8]; int li[8];
        for (int k = 0; k < 8; ++k) {
            float m = -1e30f; int mi = 0;
            for (int j = 0; j < 64; ++j) {
                float v = ls[tt][j];
                if (v > m) { m = v; mi = j; }   // strict > : lowest index wins (stable)
            }
            lv[k] = m; li[k] = mi;
            ls[tt][mi] = -1e30f;
        }
        float s = 0.f, wv[8];
        for (int k = 0; k < 8; ++k) { wv[k] = __expf(lv[k] - lv[0]); s += wv[k]; }
        float inv = 1.f / s;
        for (int k = 0; k < 8; ++k) {
            int a = (tb + tt) * TOPK + k;
            sel[a]  = li[k];
            wgtA[a] = wv[k] * inv;
        }
    }
}

// ---------------------------------------------------------------------------
// K2: per-expert stable token lists + capacity drop (matches argsort(stable)).
// Also emits the inverse map slotA[a] = e*CAP+pos (-1 if dropped) for combine.
// ---------------------------------------------------------------------------
__global__ __launch_bounds__(256) void build_lists_kernel(
    const int* __restrict__ sel,
    int* __restrict__ tok_list, int* __restrict__ slotA,
    int* __restrict__ counts)
{
    __shared__ int sc[256];
    const int e = blockIdx.x;
    const int tid = threadIdx.x;
    const int per = A_TOT / 256;
    const int a0 = tid * per;
    int cnt = 0;
    for (int i = 0; i < per; ++i) cnt += (sel[a0 + i] == e) ? 1 : 0;
    sc[tid] = cnt;
    __syncthreads();
    for (int s = 1; s < 256; s <<= 1) {
        int v = (tid >= s) ? sc[tid - s] : 0;
        __syncthreads();
        sc[tid] += v;
        __syncthreads();
    }
    int total = sc[255];
    int pos = sc[tid] - cnt;
    if (tid == 0) counts[e] = (total < CAP) ? total : CAP;
    for (int i = 0; i < per; ++i) {
        int a = a0 + i;
        if (sel[a] == e) {
            if (pos < CAP) {
                tok_list[e * CAP + pos] = a >> 3;
                slotA[a] = e * CAP + pos;
            } else {
                slotA[a] = -1;                  // dropped (never happens at CAP_FACTOR=2)
            }
            pos++;
        }
    }
}

#define MFMA16(a, b, c) __builtin_amdgcn_mfma_f32_16x16x32_f16(a, b, c, 0, 0, 0)

// ---------------------------------------------------------------------------
// K3a v5: R1's proven geometry (64 rows x 64 F-cols, 256 thr, 8192 blocks,
// wave = 64m x 16n x {G,U}, VGPR ~64, occ ~39%) + the R2-verified XOR swizzle
// on unpadded Xs[64][64] (SQ_LDS_BANK_CONFLICT 8.9M -> 0, identical
// read/write geometry). R2/R3's wider tiles cost occupancy and regressed;
// this combines R1's latency-hiding with R2's conflict-free LDS.
// ---------------------------------------------------------------------------
__global__ __launch_bounds__(256) void gemm1_kernel(
    const f16* __restrict__ xh, const f16* __restrict__ w1p,
    const f16* __restrict__ w3p, const int* __restrict__ tok_list,
    const int* __restrict__ counts, f16* __restrict__ P)
{
    const int id = blockIdx.x;
    const int x7 = id & 7, r = id >> 3;
    const int ft = r & 7, mt = (r >> 3) & 15, eh = r >> 7;
    const int e = x7 + 8 * eh;
    const int cnt = counts[e];
    const int m0 = mt * 64;
    if (m0 >= cnt) return;
    const int bf = ft * 64;

    __shared__ f16 Xs[2][64][64];
    __shared__ int tok_s[64];

    const int tid = threadIdx.x;
    const int lane = tid & 63, wv = tid >> 6;
    const int jj = lane & 15, qq = lane >> 4;
    const int sr = tid >> 3, sc = (tid & 7) * 8;
    const int swz_w = ((tid & 7) ^ (sr & 7)) * 8;     // swizzled write slot
    const int x8 = jj & 7;
    const int s0 = (qq ^ x8) * 8;                     // swizzled read slot, k-half 0
    const int s1 = ((qq + 4) ^ x8) * 8;               // swizzled read slot, k-half 1

    if (tid < 64) {
        int m = m0 + tid;
        tok_s[tid] = (m < cnt) ? tok_list[e * CAP + m] : tok_list[e * CAP];
    }
    __syncthreads();
    const size_t rowA = (size_t)tok_s[sr] * H_DIM + sc;
    const size_t rowB = (size_t)tok_s[sr + 32] * H_DIM + sc;

    const int nt = ft * 4 + wv;                       // one 16-col n-tile per wave
    const f16* w1a = w1p + ((size_t)(e * 32 + nt) * 32) * 512 + lane * 8;
    const f16* w3a = w3p + ((size_t)(e * 32 + nt) * 32) * 512 + lane * 8;

    f32x4 accG[4], accU[4];
    #pragma unroll
    for (int i = 0; i < 4; ++i) {
        accG[i] = (f32x4){0.f, 0.f, 0.f, 0.f};
        accU[i] = (f32x4){0.f, 0.f, 0.f, 0.f};
    }

    // prologue: stage k-block 0 + first weight frags
    {
        f16x8 a = *(const f16x8*)(xh + rowA);
        f16x8 b = *(const f16x8*)(xh + rowB);
        *(f16x8*)&Xs[0][sr][swz_w]      = a;
        *(f16x8*)&Xs[0][sr + 32][swz_w] = b;
    }
    f16x8 cG0 = *(const f16x8*)(w1a);
    f16x8 cG1 = *(const f16x8*)(w1a + 512);
    f16x8 cU0 = *(const f16x8*)(w3a);
    f16x8 cU1 = *(const f16x8*)(w3a + 512);

    #pragma unroll
    for (int it = 0; it < 16; ++it) {
        const int k0 = it * 64;
        __syncthreads();                       // Xs[it&1] visible; prior readers of Xs[(it+1)&1] done
        f16x8 xn0, xn1, nG0, nG1, nU0, nU1;
        if (it < 15) {                         // issue next-iter loads before MFMAs
            xn0 = *(const f16x8*)(xh + rowA + k0 + 64);
            xn1 = *(const f16x8*)(xh + rowB + k0 + 64);
            size_t kg = (size_t)(2 * it + 2) * 512;
            nG0 = *(const f16x8*)(w1a + kg);
            nG1 = *(const f16x8*)(w1a + kg + 512);
            nU0 = *(const f16x8*)(w3a + kg);
            nU1 = *(const f16x8*)(w3a + kg + 512);
        }
        const int buf = it & 1;
        #pragma unroll
        for (int m2 = 0; m2 < 4; ++m2) {
            f16x8 a0 = *(const f16x8*)&Xs[buf][m2 * 16 + jj][s0];
            f16x8 a1 = *(const f16x8*)&Xs[buf][m2 * 16 + jj][s1];
            accG[m2] = MFMA16(a0, cG0, accG[m2]);
            accU[m2] = MFMA16(a0, cU0, accU[m2]);
            accG[m2] = MFMA16(a1, cG1, accG[m2]);
            accU[m2] = MFMA16(a1, cU1, accU[m2]);
        }
        if (it < 15) {
            *(f16x8*)&Xs[buf ^ 1][sr][swz_w]      = xn0;
            *(f16x8*)&Xs[buf ^ 1][sr + 32][swz_w] = xn1;
            cG0 = nG0; cG1 = nG1; cU0 = nU0; cU1 = nU1;
        }
    }
    #pragma unroll
    for (int m2 = 0; m2 < 4; ++m2) {
        #pragma unroll
        for (int rr = 0; rr < 4; ++rr) {
            int row = m2 * 16 + qq * 4 + rr;
            float gg = accG[m2][rr], u = accU[m2][rr];
            float p = gg / (1.f + __expf(-gg)) * u;
            P[(size_t)(e * CAP + m0 + row) * F_DIM + bf + wv * 16 + jj] = (f16)p;
        }
    }
}

// ---------------------------------------------------------------------------
// K3b v5: R1's geometry (64 rows x 128 h-cols, 256 thr, 8192 blocks, wave =
// 64m x 2 n-tiles) + verified XOR-swizzled unpadded Ps[64][64].
// Plain f16 stores to slot-indexed Y[E*CAP][H]; combine applies weights.
// ---------------------------------------------------------------------------
__global__ __launch_bounds__(256) void gemm2_kernel(
    const f16* __restrict__ P, const f16* __restrict__ w2p,
    const int* __restrict__ counts, f16* __restrict__ Y)
{
    const int id = blockIdx.x;
    const int x7 = id & 7, r = id >> 3;
    const int ht = r & 7, mt = (r >> 3) & 15, eh = r >> 7;
    const int e = x7 + 8 * eh;
    const int cnt = counts[e];
    const int m0 = mt * 64;
    if (m0 >= cnt) return;
    const int h0 = ht * 128;

    __shared__ f16 Ps[2][64][64];

    const int tid = threadIdx.x;
    const int lane = tid & 63, wv = tid >> 6;
    const int jj = lane & 15, qq = lane >> 4;
    const int sr = tid >> 3, sc = (tid & 7) * 8;
    const int swz_w = ((tid & 7) ^ (sr & 7)) * 8;
    const int x8 = jj & 7;
    const int s0 = (qq ^ x8) * 8;
    const int s1 = ((qq + 4) ^ x8) * 8;

    const size_t pbase = (size_t)(e * CAP + m0) * F_DIM;
    const f16* wA = w2p + ((size_t)(e * 64 + ht * 8 + wv) * 16) * 512 + lane * 8;
    const f16* wB = w2p + ((size_t)(e * 64 + ht * 8 + wv + 4) * 16) * 512 + lane * 8;

    f32x4 accA[4], accB[4];
    #pragma unroll
    for (int i = 0; i < 4; ++i) {
        accA[i] = (f32x4){0.f, 0.f, 0.f, 0.f};
        accB[i] = (f32x4){0.f, 0.f, 0.f, 0.f};
    }

    {
        f16x8 a = *(const f16x8*)(P + pbase + (size_t)sr * F_DIM + sc);
        f16x8 b = *(const f16x8*)(P + pbase + (size_t)(sr + 32) * F_DIM + sc);
        *(f16x8*)&Ps[0][sr][swz_w]      = a;
        *(f16x8*)&Ps[0][sr + 32][swz_w] = b;
    }
    f16x8 cA0 = *(const f16x8*)(wA);
    f16x8 cA1 = *(const f16x8*)(wA + 512);
    f16x8 cB0 = *(const f16x8*)(wB);
    f16x8 cB1 = *(const f16x8*)(wB + 512);

    #pragma unroll
    for (int it = 0; it < 8; ++it) {
        const int k0 = it * 64;
        __syncthreads();
        f16x8 pn0, pn1, nA0, nA1, nB0, nB1;
        if (it < 7) {
            pn0 = *(const f16x8*)(P + pbase + (size_t)sr * F_DIM + k0 + 64 + sc);
            pn1 = *(const f16x8*)(P + pbase + (size_t)(sr + 32) * F_DIM + k0 + 64 + sc);
            size_t kg = (size_t)(2 * it + 2) * 512;
            nA0 = *(const f16x8*)(wA + kg);
            nA1 = *(const f16x8*)(wA + kg + 512);
            nB0 = *(const f16x8*)(wB + kg);
            nB1 = *(const f16x8*)(wB + kg + 512);
        }
        const int buf = it & 1;
        #pragma unroll
        for (int m2 = 0; m2 < 4; ++m2) {
            f16x8 a0 = *(const f16x8*)&Ps[buf][m2 * 16 + jj][s0];
            f16x8 a1 = *(const f16x8*)&Ps[buf][m2 * 16 + jj][s1];
            accA[m2] = MFMA16(a0, cA0, accA[m2]);
            accB[m2] = MFMA16(a0, cB0, accB[m2]);
            accA[m2] = MFMA16(a1, cA1, accA[m2]);
            accB[m2] = MFMA16(a1, cB1, accB[m2]);
        }
        if (it < 7) {
            *(f16x8*)&Ps[buf ^ 1][sr][swz_w]      = pn0;
            *(f16x8*)&Ps[buf ^ 1][sr + 32][swz_w] = pn1;
            cA0 = nA0; cA1 = nA1; cB0 = nB0; cB1 = nB1;
        }
    }
    // plain f16 stores; rows >= cnt write dead slots never referenced by combine
    f16* yb = Y + (size_t)(e * CAP + m0) * H_DIM + h0 + wv * 16 + jj;
    #pragma unroll
    for (int m2 = 0; m2 < 4; ++m2) {
        #pragma unroll
        for (int rr = 0; rr < 4; ++rr) {
            int row = m2 * 16 + qq * 4 + rr;
            yb[(size_t)row * H_DIM]      = (f16)accA[m2][rr];
            yb[(size_t)row * H_DIM + 64] = (f16)accB[m2][rr];
        }
    }
}

// ---------------------------------------------------------------------------
// K4: combine — out[t] = sum_k wgt[t,k] * Y[slot[t,k]]. Streaming gather;
// fully overwrites out (no memset needed). 2 tokens/block, 128 thr/token.
// ---------------------------------------------------------------------------
__global__ __launch_bounds__(256) void combine_kernel(
    const f16* __restrict__ Y, const int* __restrict__ slotA,
    const float* __restrict__ wgtA, float* __restrict__ out)
{
    const int tid = threadIdx.x;
    const int t  = blockIdx.x * 2 + (tid >> 7);
    const int hc = (tid & 127) * 8;
    float acc[8] = {0.f, 0.f, 0.f, 0.f, 0.f, 0.f, 0.f, 0.f};
    const int base = t * TOPK;
    #pragma unroll
    for (int k = 0; k < 8; ++k) {
        int s   = slotA[base + k];      // wave-uniform
        float w = wgtA[base + k];
        if (s >= 0) {
            f16x8 y = *(const f16x8*)(Y + (size_t)s * H_DIM + hc);
            #pragma unroll
            for (int j = 0; j < 8; ++j) acc[j] += w * (float)y[j];
        }
    }
    float4 o0 = {acc[0], acc[1], acc[2], acc[3]};
    float4 o1 = {acc[4], acc[5], acc[6], acc[7]};
    *(float4*)(out + (size_t)t * H_DIM + hc)     = o0;
    *(float4*)(out + (size_t)t * H_DIM + hc + 4) = o1;
}

extern "C" void kernel_launch(void* const* d_in, const int* in_sizes, int n_in,
                              void* d_out, int out_size, void* d_ws, size_t ws_size,
                              hipStream_t stream) {
    const float* x  = (const float*)d_in[0];   // [T,H]
    const float* wg = (const float*)d_in[1];   // [H,E]
    const float* w1 = (const float*)d_in[2];   // [E,H,F]
    const float* w3 = (const float*)d_in[3];   // [E,H,F]
    const float* w2 = (const float*)d_in[4];   // [E,F,H]

    float* out    = (float*)d_out;
    float* logits = out + (size_t)T_TOK * H_DIM;

    char* ws = (char*)d_ws;
    int*   sel      = (int*)  (ws);
    float* wgtA     = (float*)(ws + (128 << 10));
    int*   tok_list = (int*)  (ws + (256 << 10));
    int*   slotA    = (int*)  (ws + (512 << 10));
    int*   counts   = (int*)  (ws + (768 << 10));
    f16*   xh       = (f16*)  (ws + (size_t)(1 << 20));     // 8 MB
    f16*   P        = (f16*)  (ws + (size_t)(9 << 20));     // 64 MB
    f16*   w1p      = (f16*)  (ws + (size_t)(73 << 20));    // 64 MB
    f16*   w3p      = (f16*)  (ws + (size_t)(137 << 20));   // 64 MB
    f16*   w2p      = (f16*)  (ws + (size_t)(201 << 20));   // 64 MB (end 265 MB)
    // Y aliases w1p+w3p (dead after gemm1; same-stream ordering makes this safe)
    f16*   Y        = (f16*)  (ws + (size_t)(73 << 20));    // 128 MB [E*CAP, H]

    pack_all_kernel<<<24576, 256, 0, stream>>>(w1, w3, w2, w1p, w3p, w2p);   // 98304 pairs
    router_kernel<<<T_TOK / 16, 256, 0, stream>>>(x, wg, logits, sel, wgtA, xh);
    build_lists_kernel<<<E_EXP, 256, 0, stream>>>(sel, tok_list, slotA, counts);
    gemm1_kernel<<<8192, 256, 0, stream>>>(xh, w1p, w3p, tok_list, counts, P);
    gemm2_kernel<<<8192, 256, 0, stream>>>(P, w2p, counts, Y);
    combine_kernel<<<T_TOK / 2, 256, 0, stream>>>(Y, slotA, wgtA, out);
}